// Round 15
// baseline (607.042 us; speedup 1.0000x reference)
//
#include <hip/hip_runtime.h>

// ---------------- types / helpers ----------------
typedef __attribute__((ext_vector_type(4))) float f32x4;
typedef __attribute__((ext_vector_type(8))) __bf16 bf16x8;
typedef __attribute__((ext_vector_type(4))) __bf16 bf16x4;

__device__ __forceinline__ f32x4 mfma16(bf16x8 a, bf16x8 b, f32x4 c) {
  return __builtin_amdgcn_mfma_f32_16x16x32_bf16(a, b, c, 0, 0, 0);
}

// ---------------- RMSNorm (fp32 in, fp32 out + optional bf16 out), row = 2048 ----------------
__global__ __launch_bounds__(256) void rmsnorm_k(const float* __restrict__ x,
                                                 const float* __restrict__ w,
                                                 float* __restrict__ y,
                                                 __bf16* __restrict__ yb) {
  int t = blockIdx.x;
  const float* xr = x + (size_t)t * 2048;
  int d0 = threadIdx.x * 4;
  float4 v1 = *(const float4*)(xr + d0);
  float4 v2 = *(const float4*)(xr + 1024 + d0);
  float ss = v1.x*v1.x + v1.y*v1.y + v1.z*v1.z + v1.w*v1.w
           + v2.x*v2.x + v2.y*v2.y + v2.z*v2.z + v2.w*v2.w;
#pragma unroll
  for (int mk = 1; mk < 64; mk <<= 1) ss += __shfl_xor(ss, mk);
  __shared__ float red[4];
  if ((threadIdx.x & 63) == 0) red[threadIdx.x >> 6] = ss;
  __syncthreads();
  float tot = red[0] + red[1] + red[2] + red[3];
  float rs = rsqrtf(tot * (1.0f / 2048.0f) + 1e-6f);
  float* yr = y + (size_t)t * 2048;
  float4 w1 = *(const float4*)(w + d0);
  float4 w2 = *(const float4*)(w + 1024 + d0);
  float4 o1, o2;
  o1.x = v1.x*rs*w1.x; o1.y = v1.y*rs*w1.y; o1.z = v1.z*rs*w1.z; o1.w = v1.w*rs*w1.w;
  o2.x = v2.x*rs*w2.x; o2.y = v2.y*rs*w2.y; o2.z = v2.z*rs*w2.z; o2.w = v2.w*rs*w2.w;
  *(float4*)(yr + d0) = o1;
  *(float4*)(yr + 1024 + d0) = o2;
  if (yb) {
    bf16x4 b1, b2;
    b1[0] = (__bf16)o1.x; b1[1] = (__bf16)o1.y; b1[2] = (__bf16)o1.z; b1[3] = (__bf16)o1.w;
    b2[0] = (__bf16)o2.x; b2[1] = (__bf16)o2.y; b2[2] = (__bf16)o2.z; b2[3] = (__bf16)o2.w;
    *(bf16x4*)(yb + (size_t)t * 2048 + d0) = b1;
    *(bf16x4*)(yb + (size_t)t * 2048 + 1024 + d0) = b2;
  }
}

// ------------- bf16x2 split GEMM: C = [RES +] A(MxK) * B(NxK)^T, fp32 in/out -------------
// BM=128 BN=64 BK=32, 256 thr (4 waves 2x2), dbuf LDS, issue-early, 1 barrier/tile
__global__ __launch_bounds__(256) void gemm3_k(const float* __restrict__ A,
                                               const float* __restrict__ B,
                                               const float* __restrict__ RESID,
                                               float* __restrict__ C, int N, int K) {
  __shared__ __align__(16) __bf16 smAh0[128 * 40];
  __shared__ __align__(16) __bf16 smAl0[128 * 40];
  __shared__ __align__(16) __bf16 smBh0[64 * 40];
  __shared__ __align__(16) __bf16 smBl0[64 * 40];
  __shared__ __align__(16) __bf16 smAh1[128 * 40];
  __shared__ __align__(16) __bf16 smAl1[128 * 40];
  __shared__ __align__(16) __bf16 smBh1[64 * 40];
  __shared__ __align__(16) __bf16 smBl1[64 * 40];
  const int m0 = blockIdx.x * 128, n0 = blockIdx.y * 64;
  const int tid = threadIdx.x, l = tid & 63, w = tid >> 6;
  const int wm = w >> 1, wn = w & 1;
  const float* aS[4]; const float* bS[2];
  int aD[4], bD[2];
#pragma unroll
  for (int i = 0; i < 4; i++) {
    aS[i] = A + (size_t)(m0 + (tid >> 3) + 32 * i) * K + (tid & 7) * 4;
    aD[i] = ((tid >> 3) + 32 * i) * 40 + (tid & 7) * 4;
  }
#pragma unroll
  for (int i = 0; i < 2; i++) {
    bS[i] = B + (size_t)(n0 + (tid >> 3) + 32 * i) * K + (tid & 7) * 4;
    bD[i] = ((tid >> 3) + 32 * i) * 40 + (tid & 7) * 4;
  }
  float4 raE[4], rbE[2], raO[4], rbO[2];

#define GE_ISSUE_E(kt) do { _Pragma("unroll") \
  for (int i = 0; i < 4; i++) raE[i] = *(const float4*)(aS[i] + (kt)); \
  _Pragma("unroll") \
  for (int i = 0; i < 2; i++) rbE[i] = *(const float4*)(bS[i] + (kt)); } while (0)
#define GE_ISSUE_O(kt) do { _Pragma("unroll") \
  for (int i = 0; i < 4; i++) raO[i] = *(const float4*)(aS[i] + (kt)); \
  _Pragma("unroll") \
  for (int i = 0; i < 2; i++) rbO[i] = *(const float4*)(bS[i] + (kt)); } while (0)
#define SPLIT4(dh, dl, src) do { bf16x4 hv_, lv_; _Pragma("unroll") \
  for (int q_ = 0; q_ < 4; q_++) { float f_ = ((const float*)&(src))[q_]; \
    __bf16 h_ = (__bf16)f_; hv_[q_] = h_; lv_[q_] = (__bf16)(f_ - (float)h_); } \
  *(bf16x4*)(dh) = hv_; *(bf16x4*)(dl) = lv_; } while (0)
#define GE_WRITE_E(sAh, sAl, sBh, sBl) do { _Pragma("unroll") \
  for (int i = 0; i < 4; i++) SPLIT4(sAh + aD[i], sAl + aD[i], raE[i]); \
  _Pragma("unroll") \
  for (int i = 0; i < 2; i++) SPLIT4(sBh + bD[i], sBl + bD[i], rbE[i]); } while (0)
#define GE_WRITE_O(sAh, sAl, sBh, sBl) do { _Pragma("unroll") \
  for (int i = 0; i < 4; i++) SPLIT4(sAh + aD[i], sAl + aD[i], raO[i]); \
  _Pragma("unroll") \
  for (int i = 0; i < 2; i++) SPLIT4(sBh + bD[i], sBl + bD[i], rbO[i]); } while (0)

  GE_ISSUE_E(0);
  GE_ISSUE_O(32);
  GE_WRITE_E(smAh0, smAl0, smBh0, smBl0);
  __syncthreads();

  f32x4 acc[4][2] = {};
  const int afo = (wm * 64 + (l & 15)) * 40 + (l >> 4) * 8;
  const int bfo = (wn * 32 + (l & 15)) * 40 + (l >> 4) * 8;
#define GE_COMPUTE(sAh, sAl, sBh, sBl) do { \
  bf16x8 ah_[4], al_[4], bh_[2], bl_[2]; \
  _Pragma("unroll") \
  for (int f = 0; f < 4; f++) { ah_[f] = *(const bf16x8*)(sAh + afo + f * 640); \
                                al_[f] = *(const bf16x8*)(sAl + afo + f * 640); } \
  _Pragma("unroll") \
  for (int f = 0; f < 2; f++) { bh_[f] = *(const bf16x8*)(sBh + bfo + f * 640); \
                                bl_[f] = *(const bf16x8*)(sBl + bfo + f * 640); } \
  _Pragma("unroll") \
  for (int mf = 0; mf < 4; mf++) \
    _Pragma("unroll") \
    for (int nf = 0; nf < 2; nf++) { \
      acc[mf][nf] = mfma16(ah_[mf], bh_[nf], acc[mf][nf]); \
      acc[mf][nf] = mfma16(ah_[mf], bl_[nf], acc[mf][nf]); \
      acc[mf][nf] = mfma16(al_[mf], bh_[nf], acc[mf][nf]); } \
} while (0)

  const int ntiles = K >> 5;   // K=2048 -> 64 tiles (even)
  for (int it = 0; it < ntiles; it += 2) {
    GE_WRITE_O(smAh1, smAl1, smBh1, smBl1);
    if (it + 2 < ntiles) GE_ISSUE_E((it + 2) * 32);
    GE_COMPUTE(smAh0, smAl0, smBh0, smBl0);
    __syncthreads();
    if (it + 2 < ntiles) GE_WRITE_E(smAh0, smAl0, smBh0, smBl0);
    if (it + 3 < ntiles) GE_ISSUE_O((it + 3) * 32);
    GE_COMPUTE(smAh1, smAl1, smBh1, smBl1);
    __syncthreads();
  }
#undef GE_ISSUE_E
#undef GE_ISSUE_O
#undef GE_WRITE_E
#undef GE_WRITE_O
#undef GE_COMPUTE
#undef SPLIT4
#pragma unroll
  for (int mf = 0; mf < 4; mf++) {
    int row = m0 + wm * 64 + mf * 16 + ((l >> 4) << 2);
#pragma unroll
    for (int nf = 0; nf < 2; nf++) {
      int col = n0 + wn * 32 + nf * 16 + (l & 15);
#pragma unroll
      for (int r = 0; r < 4; r++) {
        float v = acc[mf][nf][r];
        if (RESID) v += RESID[(size_t)(row + r) * N + col];
        C[(size_t)(row + r) * N + col] = v;
      }
    }
  }
}

// ------------- QK per-head RMSNorm + RoPE + split into bf16 hi/lo; V split only -------------
__global__ __launch_bounds__(128) void qkr_k(const float* __restrict__ qkv,
                                             const int* __restrict__ pos,
                                             const float* __restrict__ qw,
                                             const float* __restrict__ kw,
                                             __bf16* __restrict__ qh, __bf16* __restrict__ ql,
                                             __bf16* __restrict__ kh, __bf16* __restrict__ kl,
                                             __bf16* __restrict__ vh, __bf16* __restrict__ vl) {
  int hs = blockIdx.x, t = blockIdx.y, d = threadIdx.x;
  float x = qkv[(size_t)t * 3072 + hs * 128 + d];
  __shared__ float xs[128];
  __shared__ float red[2];
  float o;
  if (hs < 20) {
    float ss = x * x;
#pragma unroll
    for (int mk = 1; mk < 64; mk <<= 1) ss += __shfl_xor(ss, mk);
    if ((d & 63) == 0) red[d >> 6] = ss;
    __syncthreads();
    float rs = rsqrtf((red[0] + red[1]) * (1.0f / 128.0f) + 1e-6f);
    const float* w = (hs < 16) ? qw : kw;
    float xn = x * rs * w[d];
    xs[d] = xn;
    __syncthreads();
    int i = d & 63;
    float invf = (float)pow(10000.0, -(double)i / 64.0);
    float ang = (float)pos[t] * invf;
    float cf = (float)cos((double)ang);
    float sf = (float)sin((double)ang);
    float rot = (d < 64) ? -xs[d + 64] : xs[d - 64];
    o = cf * xn + sf * rot;
  } else {
    o = x;
  }
  __bf16 hi = (__bf16)o;
  __bf16 lo = (__bf16)(o - (float)hi);
  if (hs < 16) {
    size_t idx = ((size_t)hs * 1024 + t) * 128 + d;
    qh[idx] = hi; ql[idx] = lo;
  } else if (hs < 20) {
    size_t idx = ((size_t)(hs - 16) * 1024 + t) * 128 + d;
    kh[idx] = hi; kl[idx] = lo;
  } else {
    size_t idx = ((size_t)(hs - 20) * 1024 + t) * 128 + d;
    vh[idx] = hi; vl[idx] = lo;
  }
}

// ------------- V transpose [kvh][t][d] -> [kvh][d][t] (hi and lo) -------------
__global__ void vtrans_k(const __bf16* __restrict__ vh, const __bf16* __restrict__ vl,
                         __bf16* __restrict__ vhT, __bf16* __restrict__ vlT) {
  __shared__ __bf16 tile[32][33];
  int kv = blockIdx.z, t0 = blockIdx.x * 32, d0 = blockIdx.y * 32;
  int tx = threadIdx.x, ty = threadIdx.y;
  tile[ty][tx] = vh[((size_t)kv * 1024 + t0 + ty) * 128 + d0 + tx];
  __syncthreads();
  vhT[((size_t)kv * 128 + d0 + ty) * 1024 + t0 + tx] = tile[tx][ty];
  __syncthreads();
  tile[ty][tx] = vl[((size_t)kv * 1024 + t0 + ty) * 128 + d0 + tx];
  __syncthreads();
  vlT[((size_t)kv * 128 + d0 + ty) * 1024 + t0 + tx] = tile[tx][ty];
}

// ------------- flash attention, causal, GQA, bf16x2 3-pass (QBLK=64, 256 thr) -------------
__global__ __launch_bounds__(256) void flash_k(const __bf16* __restrict__ qh, const __bf16* __restrict__ ql,
                                               const __bf16* __restrict__ kh, const __bf16* __restrict__ kl,
                                               const __bf16* __restrict__ vhT, const __bf16* __restrict__ vlT,
                                               float* __restrict__ attn) {
  constexpr int KH = 0, KL = 4352, VH = 8704, VL = 13824, PH = 18944, PL = 21504;
  __shared__ __align__(16) __bf16 sm[24064];
  const int qt = blockIdx.x, h = blockIdx.y;
  const int q0 = qt * 64, kvh = h >> 2;
  const int tid = threadIdx.x, l = tid & 63, w = tid >> 6;
  for (int c = tid; c < 1024; c += 256) {
    int row = c >> 4, dc = c & 15;
    size_t g = ((size_t)h * 1024 + q0 + row) * 128 + dc * 8;
    *(bf16x8*)(sm + row * 136 + dc * 8) = *(const bf16x8*)(qh + g);
    *(bf16x8*)(sm + 8704 + row * 136 + dc * 8) = *(const bf16x8*)(ql + g);
  }
  __syncthreads();
  bf16x8 fqh[4], fql[4];
  {
    int row = w * 16 + (l & 15);
    int ko = (l >> 4) * 8;
#pragma unroll
    for (int kk = 0; kk < 4; kk++) {
      fqh[kk] = *(const bf16x8*)(sm + row * 136 + kk * 32 + ko);
      fql[kk] = *(const bf16x8*)(sm + 8704 + row * 136 + kk * 32 + ko);
    }
  }
  f32x4 acc[8] = {};
  float m_run[4], l_run[4];
#pragma unroll
  for (int r = 0; r < 4; r++) { m_run[r] = -1e30f; l_run[r] = 0.0f; }
  const int ktiles = (q0 + 64) >> 5;
  for (int kt = 0; kt < ktiles; kt++) {
    const int k0 = kt * 32;
    __syncthreads();
    for (int c = tid; c < 512; c += 256) {
      int row = c >> 4, dc = c & 15;
      size_t g = ((size_t)kvh * 1024 + k0 + row) * 128 + dc * 8;
      *(bf16x8*)(sm + KH + row * 136 + dc * 8) = *(const bf16x8*)(kh + g);
      *(bf16x8*)(sm + KL + row * 136 + dc * 8) = *(const bf16x8*)(kl + g);
    }
    for (int c = tid; c < 512; c += 256) {
      int row = c >> 2, tc = c & 3;
      size_t g = ((size_t)kvh * 128 + row) * 1024 + k0 + tc * 8;
      *(bf16x8*)(sm + VH + row * 40 + tc * 8) = *(const bf16x8*)(vhT + g);
      *(bf16x8*)(sm + VL + row * 40 + tc * 8) = *(const bf16x8*)(vlT + g);
    }
    __syncthreads();
    f32x4 s[2] = {};
#pragma unroll
    for (int kk = 0; kk < 4; kk++) {
      int ko = kk * 32 + (l >> 4) * 8;
#pragma unroll
      for (int nf = 0; nf < 2; nf++) {
        int key = nf * 16 + (l & 15);
        bf16x8 bh_ = *(const bf16x8*)(sm + KH + key * 136 + ko);
        bf16x8 bl_ = *(const bf16x8*)(sm + KL + key * 136 + ko);
        s[nf] = mfma16(fqh[kk], bh_, s[nf]);
        s[nf] = mfma16(fqh[kk], bl_, s[nf]);
        s[nf] = mfma16(fql[kk], bh_, s[nf]);
      }
    }
    const float scale = 0.08838834764831845f;
    const bool need_mask = (k0 + 31 > q0);
    float p[2][4], alpha[4];
#pragma unroll
    for (int r = 0; r < 4; r++) {
      float s0 = s[0][r] * scale, s1 = s[1][r] * scale;
      if (need_mask) {
        int qi = q0 + w * 16 + ((l >> 4) << 2) + r;
        if (k0 + (l & 15) > qi) s0 = -1e30f;
        if (k0 + 16 + (l & 15) > qi) s1 = -1e30f;
      }
      float mt = fmaxf(s0, s1);
#pragma unroll
      for (int mk = 1; mk < 16; mk <<= 1) mt = fmaxf(mt, __shfl_xor(mt, mk));
      float mnew = fmaxf(m_run[r], mt);
      alpha[r] = expf(m_run[r] - mnew);
      float p0 = expf(s0 - mnew), p1 = expf(s1 - mnew);
      float rs = p0 + p1;
#pragma unroll
      for (int mk = 1; mk < 16; mk <<= 1) rs += __shfl_xor(rs, mk);
      l_run[r] = l_run[r] * alpha[r] + rs;
      m_run[r] = mnew;
      p[0][r] = p0; p[1][r] = p1;
    }
#pragma unroll
    for (int nf2 = 0; nf2 < 8; nf2++)
#pragma unroll
      for (int r = 0; r < 4; r++) acc[nf2][r] *= alpha[r];
    const int phb = PH + w * 640, plb = PL + w * 640;
#pragma unroll
    for (int nf = 0; nf < 2; nf++)
#pragma unroll
      for (int r = 0; r < 4; r++) {
        int row = ((l >> 4) << 2) + r, col = nf * 16 + (l & 15);
        __bf16 hi = (__bf16)p[nf][r];
        sm[phb + row * 40 + col] = hi;
        sm[plb + row * 40 + col] = (__bf16)(p[nf][r] - (float)hi);
      }
    bf16x8 aph = *(const bf16x8*)(sm + phb + (l & 15) * 40 + (l >> 4) * 8);
    bf16x8 apl = *(const bf16x8*)(sm + plb + (l & 15) * 40 + (l >> 4) * 8);
#pragma unroll
    for (int nf2 = 0; nf2 < 8; nf2++) {
      int drow = nf2 * 16 + (l & 15);
      bf16x8 bvh = *(const bf16x8*)(sm + VH + drow * 40 + (l >> 4) * 8);
      bf16x8 bvl = *(const bf16x8*)(sm + VL + drow * 40 + (l >> 4) * 8);
      acc[nf2] = mfma16(aph, bvh, acc[nf2]);
      acc[nf2] = mfma16(aph, bvl, acc[nf2]);
      acc[nf2] = mfma16(apl, bvh, acc[nf2]);
    }
  }
#pragma unroll
  for (int r = 0; r < 4; r++) {
    float inv = 1.0f / l_run[r];
    size_t t = q0 + w * 16 + ((l >> 4) << 2) + r;
#pragma unroll
    for (int nf2 = 0; nf2 < 8; nf2++)
      attn[t * 2048 + h * 128 + nf2 * 16 + (l & 15)] = acc[nf2][r] * inv;
  }
}

// ------------- router: fp32 logits, softmax, top-4 -------------
__global__ __launch_bounds__(256) void router_k(const float* __restrict__ h2,
                                                const float* __restrict__ rw,
                                                int* __restrict__ tidx, float* __restrict__ tw,
                                                int* __restrict__ counts) {
  int t = blockIdx.x;
  int e = threadIdx.x >> 3, sub = threadIdx.x & 7;
  const float* hrow = h2 + (size_t)t * 2048;
  const float* wrow = rw + (size_t)e * 2048;
  float acc = 0.0f;
  for (int d = sub * 4; d < 2048; d += 32) {
    float4 a = *(const float4*)(hrow + d);
    float4 b = *(const float4*)(wrow + d);
    acc += a.x * b.x + a.y * b.y + a.z * b.z + a.w * b.w;
  }
  acc += __shfl_xor(acc, 1); acc += __shfl_xor(acc, 2); acc += __shfl_xor(acc, 4);
  __shared__ float lg[32];
  if (sub == 0) lg[e] = acc;
  __syncthreads();
  if (threadIdx.x < 64) {
    int l = threadIdx.x;
    float v = (l < 32) ? lg[l] : -3e38f;
    float mx = v;
#pragma unroll
    for (int mk = 1; mk < 32; mk <<= 1) mx = fmaxf(mx, __shfl_xor(mx, mk));
    float ex = (l < 32) ? expf(v - mx) : 0.0f;
    float den = ex;
#pragma unroll
    for (int mk = 1; mk < 32; mk <<= 1) den += __shfl_xor(den, mk);
    float prob = ex / den;
    float pv = v;
    int sel_i[4]; float sel_w[4]; float wsum = 0.0f;
#pragma unroll
    for (int j = 0; j < 4; j++) {
      float m2 = pv;
#pragma unroll
      for (int mk = 1; mk < 32; mk <<= 1) m2 = fmaxf(m2, __shfl_xor(m2, mk));
      unsigned long long ball = __ballot((pv == m2) && (l < 32));
      int sel = __ffsll(ball) - 1;
      float ps = __shfl(prob, sel);
      sel_i[j] = sel; sel_w[j] = ps; wsum += ps;
      if (l == sel) pv = -3e38f;
    }
    if (l < 4) {
      tidx[t * 4 + l] = sel_i[l];
      tw[t * 4 + l] = sel_w[l] / (wsum + 1e-20f);
      atomicAdd(&counts[sel_i[l]], 1);
    }
  }
}

__global__ void zero_k(int* counts) { if (threadIdx.x < 32) counts[threadIdx.x] = 0; }

// scan + compact (expert, m-tile) schedule for BM=64 grouped GEMMs (<=96 pairs)
__global__ void scan_k(const int* __restrict__ counts, int* __restrict__ offs,
                       int* __restrict__ cursor, int* __restrict__ pair_e,
                       int* __restrict__ pair_mt) {
  int l = threadIdx.x;
  int c = (l < 32) ? counts[l] : 0;
  int x = c;
#pragma unroll
  for (int d = 1; d < 32; d <<= 1) {
    int y = __shfl_up(x, d);
    if (l >= d) x += y;
  }
  if (l < 32) { offs[l] = x - c; cursor[l] = 0; }
  if (l == 31) offs[32] = x;
  if (l == 0) {
    int n = 0;
    for (int e = 0; e < 32; e++) {
      int ce = counts[e];
      for (int m = 0; m * 64 < ce && n < 96; m++) { pair_e[n] = e; pair_mt[n] = m; n++; }
    }
    for (; n < 96; n++) { pair_e[n] = -1; pair_mt[n] = 0; }
  }
}

__global__ __launch_bounds__(256) void scatter_k(const int* __restrict__ tidx,
                                                 const int* __restrict__ offs,
                                                 int* __restrict__ cursor,
                                                 int* __restrict__ row_of_slot,
                                                 int* __restrict__ tok_of_row) {
  int p = blockIdx.x * 256 + threadIdx.x;
  if (p >= 4096) return;
  int e = tidx[p];
  int pos = atomicAdd(&cursor[e], 1);
  int row = offs[e] + pos;
  row_of_slot[p] = row;
  tok_of_row[row] = p >> 2;
}

// ------------- grouped gate/up GEMM: dbuf LDS, issue-early, BM=64 BN=128 BK=64 -------------
// 256 thr (4 waves 1x4, per-wave 64x32), grid (12 j, 96 pairs), 32 K-tiles
__global__ __launch_bounds__(256) void gateup_k(const __bf16* __restrict__ h2b,
                                                const float* __restrict__ wg,
                                                const float* __restrict__ wu,
                                                const int* __restrict__ counts,
                                                const int* __restrict__ offs,
                                                const int* __restrict__ tok_of_row,
                                                const int* __restrict__ pair_e,
                                                const int* __restrict__ pair_mt,
                                                float* __restrict__ gu) {
  const int p = blockIdx.y;
  const int e = pair_e[p];
  if (e < 0) return;
  const int mt = pair_mt[p];
  const int cnt = counts[e];
  const int j = blockIdx.x;
  const float* wsel = (j < 6) ? wg : wu;
  const int n0 = (j < 6 ? j : j - 6) * 128;
  const int gout = (j < 6) ? 0 : 768;
  __shared__ __align__(16) __bf16 smA0[64 * 72];
  __shared__ __align__(16) __bf16 smA1[64 * 72];
  __shared__ __align__(16) __bf16 smB0[128 * 72];
  __shared__ __align__(16) __bf16 smB1[128 * 72];
  __shared__ int toks[64];
  const int tid = threadIdx.x, l = tid & 63, w = tid >> 6;
  if (tid < 64) {
    int r = mt * 64 + tid;
    toks[tid] = (r < cnt) ? tok_of_row[offs[e] + r] : tok_of_row[offs[e]];
  }
  __syncthreads();
  const float* we = wsel + (size_t)e * 768 * 2048;
  const __bf16* aS[2];
  int aD[2];
#pragma unroll
  for (int i = 0; i < 2; i++) {
    aS[i] = h2b + (size_t)toks[(tid >> 3) + 32 * i] * 2048 + (tid & 7) * 8;
    aD[i] = ((tid >> 3) + 32 * i) * 72 + (tid & 7) * 8;
  }
  const float* bS[8];
  int bD[8];
#pragma unroll
  for (int i = 0; i < 8; i++) {
    bS[i] = we + (size_t)(n0 + (tid >> 4) + 16 * i) * 2048 + (tid & 15) * 4;
    bD[i] = ((tid >> 4) + 16 * i) * 72 + (tid & 15) * 4;
  }

  bf16x8 raE[2], raO[2];
  float4 rbE[8], rbO[8];

#define GU_ISSUE_E(kt) do { _Pragma("unroll") \
  for (int i = 0; i < 2; i++) raE[i] = *(const bf16x8*)(aS[i] + (kt)); \
  _Pragma("unroll") \
  for (int i = 0; i < 8; i++) rbE[i] = *(const float4*)(bS[i] + (kt)); } while (0)
#define GU_ISSUE_O(kt) do { _Pragma("unroll") \
  for (int i = 0; i < 2; i++) raO[i] = *(const bf16x8*)(aS[i] + (kt)); \
  _Pragma("unroll") \
  for (int i = 0; i < 8; i++) rbO[i] = *(const float4*)(bS[i] + (kt)); } while (0)
#define CVT4(dst, src) do { bf16x4 hv_; _Pragma("unroll") \
  for (int q_ = 0; q_ < 4; q_++) hv_[q_] = (__bf16)((const float*)&(src))[q_]; \
  *(bf16x4*)(dst) = hv_; } while (0)
#define GU_WRITE_E(smA, smB) do { _Pragma("unroll") \
  for (int i = 0; i < 2; i++) *(bf16x8*)(smA + aD[i]) = raE[i]; \
  _Pragma("unroll") \
  for (int i = 0; i < 8; i++) CVT4(smB + bD[i], rbE[i]); } while (0)
#define GU_WRITE_O(smA, smB) do { _Pragma("unroll") \
  for (int i = 0; i < 2; i++) *(bf16x8*)(smA + aD[i]) = raO[i]; \
  _Pragma("unroll") \
  for (int i = 0; i < 8; i++) CVT4(smB + bD[i], rbO[i]); } while (0)

  GU_ISSUE_E(0);
  GU_ISSUE_O(64);
  GU_WRITE_E(smA0, smB0);
  __syncthreads();

  f32x4 acc[4][2] = {};
  const int afo = ((l & 15)) * 72 + (l >> 4) * 8;
  const int bfo = (w * 32 + (l & 15)) * 72 + (l >> 4) * 8;
#define GU_COMPUTE(smA, smB) do { _Pragma("unroll") \
  for (int kk = 0; kk < 2; kk++) { \
    bf16x8 af_[4], bf_[2]; \
    _Pragma("unroll") \
    for (int f = 0; f < 4; f++) af_[f] = *(const bf16x8*)(smA + afo + kk * 32 + f * 1152); \
    _Pragma("unroll") \
    for (int f = 0; f < 2; f++) bf_[f] = *(const bf16x8*)(smB + bfo + kk * 32 + f * 1152); \
    _Pragma("unroll") \
    for (int mf = 0; mf < 4; mf++) \
      _Pragma("unroll") \
      for (int nf = 0; nf < 2; nf++) acc[mf][nf] = mfma16(af_[mf], bf_[nf], acc[mf][nf]); } \
} while (0)

  for (int it = 0; it < 32; it += 2) {
    GU_WRITE_O(smA1, smB1);
    if (it + 2 < 32) GU_ISSUE_E((it + 2) * 64);
    GU_COMPUTE(smA0, smB0);
    __syncthreads();
    if (it + 2 < 32) GU_WRITE_E(smA0, smB0);
    if (it + 3 < 32) GU_ISSUE_O((it + 3) * 64);
    GU_COMPUTE(smA1, smB1);
    __syncthreads();
  }
#undef GU_ISSUE_E
#undef GU_ISSUE_O
#undef GU_WRITE_E
#undef GU_WRITE_O
#undef GU_COMPUTE
#undef CVT4
#pragma unroll
  for (int mf = 0; mf < 4; mf++) {
    int rr = mt * 64 + mf * 16 + ((l >> 4) << 2);
#pragma unroll
    for (int nf = 0; nf < 2; nf++) {
      int col = gout + n0 + w * 32 + nf * 16 + (l & 15);
#pragma unroll
      for (int r = 0; r < 4; r++)
        if (rr + r < cnt)
          gu[(size_t)(offs[e] + rr + r) * 1536 + col] = acc[mf][nf][r];
    }
  }
}

// ------------- grouped down GEMM with FUSED silu: dout(bf16) = [silu(g)*u] * w_down[e]^T -------------
// A staged on the fly from fp32 gu (cols 0-767 gate, 768-1535 up); same rounding as old silu_k.
// 256 thr (4 waves 1x4), grid (16 nt, 96 pairs), 12 K-tiles, BM=64 BN=128 BK=64
__global__ __launch_bounds__(256) void down_k(const float* __restrict__ gu,
                                              const float* __restrict__ wd,
                                              const int* __restrict__ counts,
                                              const int* __restrict__ offs,
                                              const int* __restrict__ pair_e,
                                              const int* __restrict__ pair_mt,
                                              __bf16* __restrict__ dout) {
  const int p = blockIdx.y;
  const int e = pair_e[p];
  if (e < 0) return;
  const int mt = pair_mt[p];
  const int cnt = counts[e];
  const int n0 = blockIdx.x * 128;
  __shared__ __align__(16) __bf16 smA0[64 * 72];
  __shared__ __align__(16) __bf16 smA1[64 * 72];
  __shared__ __align__(16) __bf16 smB0[128 * 72];
  __shared__ __align__(16) __bf16 smB1[128 * 72];
  const int tid = threadIdx.x, l = tid & 63, w = tid >> 6;
  const float* wde = wd + (size_t)e * 2048 * 768;
  const int base = offs[e] + mt * 64;
  const float* gS[2];   // gate source (fp32), up at +768
  int aD[2];
#pragma unroll
  for (int i = 0; i < 2; i++) {
    int rg = base + (tid >> 3) + 32 * i; if (rg > 4095) rg = 4095;
    gS[i] = gu + (size_t)rg * 1536 + (tid & 7) * 8;
    aD[i] = ((tid >> 3) + 32 * i) * 72 + (tid & 7) * 8;
  }
  const float* bS[8];
  int bD[8];
#pragma unroll
  for (int i = 0; i < 8; i++) {
    bS[i] = wde + (size_t)(n0 + (tid >> 4) + 16 * i) * 768 + (tid & 15) * 4;
    bD[i] = ((tid >> 4) + 16 * i) * 72 + (tid & 15) * 4;
  }

  float4 gE[2][2], uE[2][2], gO[2][2], uO[2][2];
  float4 rbE[8], rbO[8];

#define DN_ISSUE_E(kt) do { _Pragma("unroll") \
  for (int i = 0; i < 2; i++) { \
    gE[i][0] = *(const float4*)(gS[i] + (kt)); gE[i][1] = *(const float4*)(gS[i] + (kt) + 4); \
    uE[i][0] = *(const float4*)(gS[i] + 768 + (kt)); uE[i][1] = *(const float4*)(gS[i] + 768 + (kt) + 4); } \
  _Pragma("unroll") \
  for (int i = 0; i < 8; i++) rbE[i] = *(const float4*)(bS[i] + (kt)); } while (0)
#define DN_ISSUE_O(kt) do { _Pragma("unroll") \
  for (int i = 0; i < 2; i++) { \
    gO[i][0] = *(const float4*)(gS[i] + (kt)); gO[i][1] = *(const float4*)(gS[i] + (kt) + 4); \
    uO[i][0] = *(const float4*)(gS[i] + 768 + (kt)); uO[i][1] = *(const float4*)(gS[i] + 768 + (kt) + 4); } \
  _Pragma("unroll") \
  for (int i = 0; i < 8; i++) rbO[i] = *(const float4*)(bS[i] + (kt)); } while (0)
#define CVT4(dst, src) do { bf16x4 hv_; _Pragma("unroll") \
  for (int q_ = 0; q_ < 4; q_++) hv_[q_] = (__bf16)((const float*)&(src))[q_]; \
  *(bf16x4*)(dst) = hv_; } while (0)
#define DN_WRITE_X(smA, smB, gR, uR, rbR) do { _Pragma("unroll") \
  for (int i = 0; i < 2; i++) { bf16x8 av_; \
    _Pragma("unroll") \
    for (int h_ = 0; h_ < 2; h_++) \
      _Pragma("unroll") \
      for (int q_ = 0; q_ < 4; q_++) { \
        float g_ = ((const float*)&gR[i][h_])[q_]; \
        float u_ = ((const float*)&uR[i][h_])[q_]; \
        av_[h_ * 4 + q_] = (__bf16)(g_ / (1.0f + expf(-g_)) * u_); } \
    *(bf16x8*)(smA + aD[i]) = av_; } \
  _Pragma("unroll") \
  for (int i = 0; i < 8; i++) CVT4(smB + bD[i], rbR[i]); } while (0)

  DN_ISSUE_E(0);
  DN_ISSUE_O(64);
  DN_WRITE_X(smA0, smB0, gE, uE, rbE);
  __syncthreads();

  f32x4 acc[4][2] = {};
  const int afo = ((l & 15)) * 72 + (l >> 4) * 8;
  const int bfo = (w * 32 + (l & 15)) * 72 + (l >> 4) * 8;
#define DN_COMPUTE(smA, smB) do { _Pragma("unroll") \
  for (int kk = 0; kk < 2; kk++) { \
    bf16x8 af_[4], bf_[2]; \
    _Pragma("unroll") \
    for (int f = 0; f < 4; f++) af_[f] = *(const bf16x8*)(smA + afo + kk * 32 + f * 1152); \
    _Pragma("unroll") \
    for (int f = 0; f < 2; f++) bf_[f] = *(const bf16x8*)(smB + bfo + kk * 32 + f * 1152); \
    _Pragma("unroll") \
    for (int mf = 0; mf < 4; mf++) \
      _Pragma("unroll") \
      for (int nf = 0; nf < 2; nf++) acc[mf][nf] = mfma16(af_[mf], bf_[nf], acc[mf][nf]); } \
} while (0)

  for (int it = 0; it < 12; it += 2) {
    DN_WRITE_X(smA1, smB1, gO, uO, rbO);
    if (it + 2 < 12) DN_ISSUE_E((it + 2) * 64);
    DN_COMPUTE(smA0, smB0);
    __syncthreads();
    if (it + 2 < 12) DN_WRITE_X(smA0, smB0, gE, uE, rbE);
    if (it + 3 < 12) DN_ISSUE_O((it + 3) * 64);
    DN_COMPUTE(smA1, smB1);
    __syncthreads();
  }
#undef DN_ISSUE_E
#undef DN_ISSUE_O
#undef DN_WRITE_X
#undef DN_COMPUTE
#undef CVT4
#pragma unroll
  for (int mf = 0; mf < 4; mf++) {
    int rr = mt * 64 + mf * 16 + ((l >> 4) << 2);
#pragma unroll
    for (int nf = 0; nf < 2; nf++) {
      int col = n0 + w * 32 + nf * 16 + (l & 15);
#pragma unroll
      for (int r = 0; r < 4; r++)
        if (rr + r < cnt)
          dout[(size_t)(offs[e] + rr + r) * 2048 + col] = (__bf16)acc[mf][nf][r];
    }
  }
}

// ------------- combine: out = hidden + sum_k w_k * dout_bf16[row_of_slot[t*4+k]] -------------
__global__ __launch_bounds__(256) void combine_k(const float* __restrict__ hidden,
                                                 const __bf16* __restrict__ dout,
                                                 const int* __restrict__ row_of_slot,
                                                 const float* __restrict__ tw,
                                                 float* __restrict__ out) {
  int t = blockIdx.x;
  int r0 = row_of_slot[t * 4 + 0], r1 = row_of_slot[t * 4 + 1];
  int r2 = row_of_slot[t * 4 + 2], r3 = row_of_slot[t * 4 + 3];
  float w0 = tw[t * 4 + 0], w1 = tw[t * 4 + 1], w2 = tw[t * 4 + 2], w3 = tw[t * 4 + 3];
  const float* h = hidden + (size_t)t * 2048;
  float* o = out + (size_t)t * 2048;
  int d = threadIdx.x * 8;
  float4 hv1 = *(const float4*)(h + d);
  float4 hv2 = *(const float4*)(h + d + 4);
  bf16x8 a0 = *(const bf16x8*)(dout + (size_t)r0 * 2048 + d);
  bf16x8 a1 = *(const bf16x8*)(dout + (size_t)r1 * 2048 + d);
  bf16x8 a2 = *(const bf16x8*)(dout + (size_t)r2 * 2048 + d);
  bf16x8 a3 = *(const bf16x8*)(dout + (size_t)r3 * 2048 + d);
  float ov[8];
#pragma unroll
  for (int j = 0; j < 8; j++) {
    float hj = (j < 4) ? ((const float*)&hv1)[j] : ((const float*)&hv2)[j - 4];
    ov[j] = hj + w0 * (float)a0[j] + w1 * (float)a1[j] + w2 * (float)a2[j] + w3 * (float)a3[j];
  }
  float4 o1, o2;
  o1.x = ov[0]; o1.y = ov[1]; o1.z = ov[2]; o1.w = ov[3];
  o2.x = ov[4]; o2.y = ov[5]; o2.z = ov[6]; o2.w = ov[7];
  *(float4*)(o + d) = o1;
  *(float4*)(o + d + 4) = o2;
}

// ---------------- launcher ----------------
extern "C" void kernel_launch(void* const* d_in, const int* in_sizes, int n_in,
                              void* d_out, int out_size, void* d_ws, size_t ws_size,
                              hipStream_t stream) {
  (void)in_sizes; (void)n_in; (void)out_size; (void)ws_size;
  const float* hs   = (const float*)d_in[0];
  const int*   pos  = (const int*)d_in[1];
  const float* ln1w = (const float*)d_in[2];
  const float* wqkv = (const float*)d_in[3];
  const float* qnw  = (const float*)d_in[4];
  const float* knw  = (const float*)d_in[5];
  const float* wo   = (const float*)d_in[6];
  const float* ln2w = (const float*)d_in[7];
  const float* rw   = (const float*)d_in[8];
  const float* wg   = (const float*)d_in[9];
  const float* wu   = (const float*)d_in[10];
  const float* wd   = (const float*)d_in[11];
  float* out = (float*)d_out;
  char* ws = (char*)d_ws;

  // layout:
  //   [0, 25.2M):        h1 (attn) -> gu [4096][1536] f32 (gateup..down; read by fused down)
  //   [8.4M, 21M):       qkv (dies at qkr_k; inside gu region, no live overlap)
  //   [21M, 35.65M):     q/k/v hi/lo, vT (attn only)
  //   [25.2M, 41.94M):   dout [4096][2048] bf16 (down..combine; overlaps dead q/k/v + dead h2b)
  //   [35.65M, 39.84M):  attn (dies at O-proj) -> h2b bf16 (rmsnorm2..gateup; dead before down)
  //   [41.94M, 44M):     pair_e/pair_mt (scan..down)
  //   [44M, 52.4M):      hidden ; [52.4M, 60.8M): h2 ; small buffers at 60.8M+
  float*  h1     = (float*)(ws + 0);
  float*  gu     = (float*)(ws + 0);            // [4096][1536] f32
  float*  qkv    = (float*)(ws + 8388608);
  __bf16* qh     = (__bf16*)(ws + 20971520);
  __bf16* ql     = (__bf16*)(ws + 25165824);
  __bf16* kh     = (__bf16*)(ws + 29360128);
  __bf16* kl     = (__bf16*)(ws + 30408704);
  __bf16* vh     = (__bf16*)(ws + 31457280);
  __bf16* vl     = (__bf16*)(ws + 32505856);
  __bf16* vhT    = (__bf16*)(ws + 33554432);
  __bf16* vlT    = (__bf16*)(ws + 34603008);
  __bf16* dout   = (__bf16*)(ws + 25165824);    // [4096][2048] bf16 (after attn phase dead)
  float*  attn   = (float*)(ws + 35651584);
  __bf16* h2b    = (__bf16*)(ws + 35651584);    // [1024][2048] bf16
  int*    pair_e = (int*)(ws + 41943040);       // [96]
  int*    pair_mt= (int*)(ws + 41943552);       // [96]
  float*  hidden = (float*)(ws + 44040192);
  float*  h2     = (float*)(ws + 52428800);
  int*    tidx   = (int*)(ws + 60817408);
  float*  tw     = (float*)(ws + 60833792);
  int*    counts = (int*)(ws + 60850176);
  int*    offs   = (int*)(ws + 60850432);
  int*    cursor = (int*)(ws + 60850688);
  int*    row_of_slot = (int*)(ws + 60850944);
  int*    tok_of_row  = (int*)(ws + 60867328);

  // attention block
  rmsnorm_k<<<1024, 256, 0, stream>>>(hs, ln1w, h1, nullptr);
  gemm3_k<<<dim3(8, 48), 256, 0, stream>>>(h1, wqkv, nullptr, qkv, 3072, 2048);
  qkr_k<<<dim3(24, 1024), 128, 0, stream>>>(qkv, pos, qnw, knw, qh, ql, kh, kl, vh, vl);
  vtrans_k<<<dim3(32, 4, 4), dim3(32, 32), 0, stream>>>(vh, vl, vhT, vlT);
  flash_k<<<dim3(16, 16), 256, 0, stream>>>(qh, ql, kh, kl, vhT, vlT, attn);
  gemm3_k<<<dim3(8, 32), 256, 0, stream>>>(attn, wo, hs, hidden, 2048, 2048);

  // MoE block
  rmsnorm_k<<<1024, 256, 0, stream>>>(hidden, ln2w, h2, h2b);
  zero_k<<<1, 64, 0, stream>>>(counts);
  router_k<<<1024, 256, 0, stream>>>(h2, rw, tidx, tw, counts);
  scan_k<<<1, 64, 0, stream>>>(counts, offs, cursor, pair_e, pair_mt);
  scatter_k<<<16, 256, 0, stream>>>(tidx, offs, cursor, row_of_slot, tok_of_row);
  gateup_k<<<dim3(12, 96), 256, 0, stream>>>(h2b, wg, wu, counts, offs, tok_of_row, pair_e, pair_mt, gu);
  down_k<<<dim3(16, 96), 256, 0, stream>>>(gu, wd, counts, offs, pair_e, pair_mt, dout);
  combine_k<<<1024, 256, 0, stream>>>(hidden, dout, row_of_slot, tw, out);
}

// Round 16
// 543.345 us; speedup vs baseline: 1.1172x; 1.1172x over previous
//
#include <hip/hip_runtime.h>

// ---------------- types / helpers ----------------
typedef __attribute__((ext_vector_type(4))) float f32x4;
typedef __attribute__((ext_vector_type(8))) __bf16 bf16x8;
typedef __attribute__((ext_vector_type(4))) __bf16 bf16x4;

__device__ __forceinline__ f32x4 mfma16(bf16x8 a, bf16x8 b, f32x4 c) {
  return __builtin_amdgcn_mfma_f32_16x16x32_bf16(a, b, c, 0, 0, 0);
}

// ---------------- RMSNorm (fp32 in, fp32 out + optional bf16 out), row = 2048 ----------------
__global__ __launch_bounds__(256) void rmsnorm_k(const float* __restrict__ x,
                                                 const float* __restrict__ w,
                                                 float* __restrict__ y,
                                                 __bf16* __restrict__ yb) {
  int t = blockIdx.x;
  const float* xr = x + (size_t)t * 2048;
  int d0 = threadIdx.x * 4;
  float4 v1 = *(const float4*)(xr + d0);
  float4 v2 = *(const float4*)(xr + 1024 + d0);
  float ss = v1.x*v1.x + v1.y*v1.y + v1.z*v1.z + v1.w*v1.w
           + v2.x*v2.x + v2.y*v2.y + v2.z*v2.z + v2.w*v2.w;
#pragma unroll
  for (int mk = 1; mk < 64; mk <<= 1) ss += __shfl_xor(ss, mk);
  __shared__ float red[4];
  if ((threadIdx.x & 63) == 0) red[threadIdx.x >> 6] = ss;
  __syncthreads();
  float tot = red[0] + red[1] + red[2] + red[3];
  float rs = rsqrtf(tot * (1.0f / 2048.0f) + 1e-6f);
  float* yr = y + (size_t)t * 2048;
  float4 w1 = *(const float4*)(w + d0);
  float4 w2 = *(const float4*)(w + 1024 + d0);
  float4 o1, o2;
  o1.x = v1.x*rs*w1.x; o1.y = v1.y*rs*w1.y; o1.z = v1.z*rs*w1.z; o1.w = v1.w*rs*w1.w;
  o2.x = v2.x*rs*w2.x; o2.y = v2.y*rs*w2.y; o2.z = v2.z*rs*w2.z; o2.w = v2.w*rs*w2.w;
  *(float4*)(yr + d0) = o1;
  *(float4*)(yr + 1024 + d0) = o2;
  if (yb) {
    bf16x4 b1, b2;
    b1[0] = (__bf16)o1.x; b1[1] = (__bf16)o1.y; b1[2] = (__bf16)o1.z; b1[3] = (__bf16)o1.w;
    b2[0] = (__bf16)o2.x; b2[1] = (__bf16)o2.y; b2[2] = (__bf16)o2.z; b2[3] = (__bf16)o2.w;
    *(bf16x4*)(yb + (size_t)t * 2048 + d0) = b1;
    *(bf16x4*)(yb + (size_t)t * 2048 + 1024 + d0) = b2;
  }
}

// ------------- bf16x2 split GEMM: C = [RES +] A(MxK) * B(NxK)^T, fp32 in/out -------------
// BM=128 BN=64 BK=32, 256 thr (4 waves 2x2), dbuf LDS, issue-early, 1 barrier/tile
__global__ __launch_bounds__(256) void gemm3_k(const float* __restrict__ A,
                                               const float* __restrict__ B,
                                               const float* __restrict__ RESID,
                                               float* __restrict__ C, int N, int K) {
  __shared__ __align__(16) __bf16 smAh0[128 * 40];
  __shared__ __align__(16) __bf16 smAl0[128 * 40];
  __shared__ __align__(16) __bf16 smBh0[64 * 40];
  __shared__ __align__(16) __bf16 smBl0[64 * 40];
  __shared__ __align__(16) __bf16 smAh1[128 * 40];
  __shared__ __align__(16) __bf16 smAl1[128 * 40];
  __shared__ __align__(16) __bf16 smBh1[64 * 40];
  __shared__ __align__(16) __bf16 smBl1[64 * 40];
  const int m0 = blockIdx.x * 128, n0 = blockIdx.y * 64;
  const int tid = threadIdx.x, l = tid & 63, w = tid >> 6;
  const int wm = w >> 1, wn = w & 1;
  const float* aS[4]; const float* bS[2];
  int aD[4], bD[2];
#pragma unroll
  for (int i = 0; i < 4; i++) {
    aS[i] = A + (size_t)(m0 + (tid >> 3) + 32 * i) * K + (tid & 7) * 4;
    aD[i] = ((tid >> 3) + 32 * i) * 40 + (tid & 7) * 4;
  }
#pragma unroll
  for (int i = 0; i < 2; i++) {
    bS[i] = B + (size_t)(n0 + (tid >> 3) + 32 * i) * K + (tid & 7) * 4;
    bD[i] = ((tid >> 3) + 32 * i) * 40 + (tid & 7) * 4;
  }
  float4 raE[4], rbE[2], raO[4], rbO[2];

#define GE_ISSUE_E(kt) do { _Pragma("unroll") \
  for (int i = 0; i < 4; i++) raE[i] = *(const float4*)(aS[i] + (kt)); \
  _Pragma("unroll") \
  for (int i = 0; i < 2; i++) rbE[i] = *(const float4*)(bS[i] + (kt)); } while (0)
#define GE_ISSUE_O(kt) do { _Pragma("unroll") \
  for (int i = 0; i < 4; i++) raO[i] = *(const float4*)(aS[i] + (kt)); \
  _Pragma("unroll") \
  for (int i = 0; i < 2; i++) rbO[i] = *(const float4*)(bS[i] + (kt)); } while (0)
#define SPLIT4(dh, dl, src) do { bf16x4 hv_, lv_; _Pragma("unroll") \
  for (int q_ = 0; q_ < 4; q_++) { float f_ = ((const float*)&(src))[q_]; \
    __bf16 h_ = (__bf16)f_; hv_[q_] = h_; lv_[q_] = (__bf16)(f_ - (float)h_); } \
  *(bf16x4*)(dh) = hv_; *(bf16x4*)(dl) = lv_; } while (0)
#define GE_WRITE_E(sAh, sAl, sBh, sBl) do { _Pragma("unroll") \
  for (int i = 0; i < 4; i++) SPLIT4(sAh + aD[i], sAl + aD[i], raE[i]); \
  _Pragma("unroll") \
  for (int i = 0; i < 2; i++) SPLIT4(sBh + bD[i], sBl + bD[i], rbE[i]); } while (0)
#define GE_WRITE_O(sAh, sAl, sBh, sBl) do { _Pragma("unroll") \
  for (int i = 0; i < 4; i++) SPLIT4(sAh + aD[i], sAl + aD[i], raO[i]); \
  _Pragma("unroll") \
  for (int i = 0; i < 2; i++) SPLIT4(sBh + bD[i], sBl + bD[i], rbO[i]); } while (0)

  GE_ISSUE_E(0);
  GE_ISSUE_O(32);
  GE_WRITE_E(smAh0, smAl0, smBh0, smBl0);
  __syncthreads();

  f32x4 acc[4][2] = {};
  const int afo = (wm * 64 + (l & 15)) * 40 + (l >> 4) * 8;
  const int bfo = (wn * 32 + (l & 15)) * 40 + (l >> 4) * 8;
#define GE_COMPUTE(sAh, sAl, sBh, sBl) do { \
  bf16x8 ah_[4], al_[4], bh_[2], bl_[2]; \
  _Pragma("unroll") \
  for (int f = 0; f < 4; f++) { ah_[f] = *(const bf16x8*)(sAh + afo + f * 640); \
                                al_[f] = *(const bf16x8*)(sAl + afo + f * 640); } \
  _Pragma("unroll") \
  for (int f = 0; f < 2; f++) { bh_[f] = *(const bf16x8*)(sBh + bfo + f * 640); \
                                bl_[f] = *(const bf16x8*)(sBl + bfo + f * 640); } \
  _Pragma("unroll") \
  for (int mf = 0; mf < 4; mf++) \
    _Pragma("unroll") \
    for (int nf = 0; nf < 2; nf++) { \
      acc[mf][nf] = mfma16(ah_[mf], bh_[nf], acc[mf][nf]); \
      acc[mf][nf] = mfma16(ah_[mf], bl_[nf], acc[mf][nf]); \
      acc[mf][nf] = mfma16(al_[mf], bh_[nf], acc[mf][nf]); } \
} while (0)

  const int ntiles = K >> 5;   // K=2048 -> 64 tiles (even)
  for (int it = 0; it < ntiles; it += 2) {
    GE_WRITE_O(smAh1, smAl1, smBh1, smBl1);
    if (it + 2 < ntiles) GE_ISSUE_E((it + 2) * 32);
    GE_COMPUTE(smAh0, smAl0, smBh0, smBl0);
    __syncthreads();
    if (it + 2 < ntiles) GE_WRITE_E(smAh0, smAl0, smBh0, smBl0);
    if (it + 3 < ntiles) GE_ISSUE_O((it + 3) * 32);
    GE_COMPUTE(smAh1, smAl1, smBh1, smBl1);
    __syncthreads();
  }
#undef GE_ISSUE_E
#undef GE_ISSUE_O
#undef GE_WRITE_E
#undef GE_WRITE_O
#undef GE_COMPUTE
#undef SPLIT4
#pragma unroll
  for (int mf = 0; mf < 4; mf++) {
    int row = m0 + wm * 64 + mf * 16 + ((l >> 4) << 2);
#pragma unroll
    for (int nf = 0; nf < 2; nf++) {
      int col = n0 + wn * 32 + nf * 16 + (l & 15);
#pragma unroll
      for (int r = 0; r < 4; r++) {
        float v = acc[mf][nf][r];
        if (RESID) v += RESID[(size_t)(row + r) * N + col];
        C[(size_t)(row + r) * N + col] = v;
      }
    }
  }
}

// ------------- QK per-head RMSNorm + RoPE + split into bf16 hi/lo; V split only -------------
__global__ __launch_bounds__(128) void qkr_k(const float* __restrict__ qkv,
                                             const int* __restrict__ pos,
                                             const float* __restrict__ qw,
                                             const float* __restrict__ kw,
                                             __bf16* __restrict__ qh, __bf16* __restrict__ ql,
                                             __bf16* __restrict__ kh, __bf16* __restrict__ kl,
                                             __bf16* __restrict__ vh, __bf16* __restrict__ vl) {
  int hs = blockIdx.x, t = blockIdx.y, d = threadIdx.x;
  float x = qkv[(size_t)t * 3072 + hs * 128 + d];
  __shared__ float xs[128];
  __shared__ float red[2];
  float o;
  if (hs < 20) {
    float ss = x * x;
#pragma unroll
    for (int mk = 1; mk < 64; mk <<= 1) ss += __shfl_xor(ss, mk);
    if ((d & 63) == 0) red[d >> 6] = ss;
    __syncthreads();
    float rs = rsqrtf((red[0] + red[1]) * (1.0f / 128.0f) + 1e-6f);
    const float* w = (hs < 16) ? qw : kw;
    float xn = x * rs * w[d];
    xs[d] = xn;
    __syncthreads();
    int i = d & 63;
    float invf = (float)pow(10000.0, -(double)i / 64.0);
    float ang = (float)pos[t] * invf;
    float cf = (float)cos((double)ang);
    float sf = (float)sin((double)ang);
    float rot = (d < 64) ? -xs[d + 64] : xs[d - 64];
    o = cf * xn + sf * rot;
  } else {
    o = x;
  }
  __bf16 hi = (__bf16)o;
  __bf16 lo = (__bf16)(o - (float)hi);
  if (hs < 16) {
    size_t idx = ((size_t)hs * 1024 + t) * 128 + d;
    qh[idx] = hi; ql[idx] = lo;
  } else if (hs < 20) {
    size_t idx = ((size_t)(hs - 16) * 1024 + t) * 128 + d;
    kh[idx] = hi; kl[idx] = lo;
  } else {
    size_t idx = ((size_t)(hs - 20) * 1024 + t) * 128 + d;
    vh[idx] = hi; vl[idx] = lo;
  }
}

// ------------- V transpose [kvh][t][d] -> [kvh][d][t] (hi and lo) -------------
__global__ void vtrans_k(const __bf16* __restrict__ vh, const __bf16* __restrict__ vl,
                         __bf16* __restrict__ vhT, __bf16* __restrict__ vlT) {
  __shared__ __bf16 tile[32][33];
  int kv = blockIdx.z, t0 = blockIdx.x * 32, d0 = blockIdx.y * 32;
  int tx = threadIdx.x, ty = threadIdx.y;
  tile[ty][tx] = vh[((size_t)kv * 1024 + t0 + ty) * 128 + d0 + tx];
  __syncthreads();
  vhT[((size_t)kv * 128 + d0 + ty) * 1024 + t0 + tx] = tile[tx][ty];
  __syncthreads();
  tile[ty][tx] = vl[((size_t)kv * 1024 + t0 + ty) * 128 + d0 + tx];
  __syncthreads();
  vlT[((size_t)kv * 128 + d0 + ty) * 1024 + t0 + tx] = tile[tx][ty];
}

// ------------- flash attention, causal, GQA, bf16x2 3-pass (QBLK=64, 256 thr) -------------
__global__ __launch_bounds__(256) void flash_k(const __bf16* __restrict__ qh, const __bf16* __restrict__ ql,
                                               const __bf16* __restrict__ kh, const __bf16* __restrict__ kl,
                                               const __bf16* __restrict__ vhT, const __bf16* __restrict__ vlT,
                                               float* __restrict__ attn) {
  constexpr int KH = 0, KL = 4352, VH = 8704, VL = 13824, PH = 18944, PL = 21504;
  __shared__ __align__(16) __bf16 sm[24064];
  const int qt = blockIdx.x, h = blockIdx.y;
  const int q0 = qt * 64, kvh = h >> 2;
  const int tid = threadIdx.x, l = tid & 63, w = tid >> 6;
  for (int c = tid; c < 1024; c += 256) {
    int row = c >> 4, dc = c & 15;
    size_t g = ((size_t)h * 1024 + q0 + row) * 128 + dc * 8;
    *(bf16x8*)(sm + row * 136 + dc * 8) = *(const bf16x8*)(qh + g);
    *(bf16x8*)(sm + 8704 + row * 136 + dc * 8) = *(const bf16x8*)(ql + g);
  }
  __syncthreads();
  bf16x8 fqh[4], fql[4];
  {
    int row = w * 16 + (l & 15);
    int ko = (l >> 4) * 8;
#pragma unroll
    for (int kk = 0; kk < 4; kk++) {
      fqh[kk] = *(const bf16x8*)(sm + row * 136 + kk * 32 + ko);
      fql[kk] = *(const bf16x8*)(sm + 8704 + row * 136 + kk * 32 + ko);
    }
  }
  f32x4 acc[8] = {};
  float m_run[4], l_run[4];
#pragma unroll
  for (int r = 0; r < 4; r++) { m_run[r] = -1e30f; l_run[r] = 0.0f; }
  const int ktiles = (q0 + 64) >> 5;
  for (int kt = 0; kt < ktiles; kt++) {
    const int k0 = kt * 32;
    __syncthreads();
    for (int c = tid; c < 512; c += 256) {
      int row = c >> 4, dc = c & 15;
      size_t g = ((size_t)kvh * 1024 + k0 + row) * 128 + dc * 8;
      *(bf16x8*)(sm + KH + row * 136 + dc * 8) = *(const bf16x8*)(kh + g);
      *(bf16x8*)(sm + KL + row * 136 + dc * 8) = *(const bf16x8*)(kl + g);
    }
    for (int c = tid; c < 512; c += 256) {
      int row = c >> 2, tc = c & 3;
      size_t g = ((size_t)kvh * 128 + row) * 1024 + k0 + tc * 8;
      *(bf16x8*)(sm + VH + row * 40 + tc * 8) = *(const bf16x8*)(vhT + g);
      *(bf16x8*)(sm + VL + row * 40 + tc * 8) = *(const bf16x8*)(vlT + g);
    }
    __syncthreads();
    f32x4 s[2] = {};
#pragma unroll
    for (int kk = 0; kk < 4; kk++) {
      int ko = kk * 32 + (l >> 4) * 8;
#pragma unroll
      for (int nf = 0; nf < 2; nf++) {
        int key = nf * 16 + (l & 15);
        bf16x8 bh_ = *(const bf16x8*)(sm + KH + key * 136 + ko);
        bf16x8 bl_ = *(const bf16x8*)(sm + KL + key * 136 + ko);
        s[nf] = mfma16(fqh[kk], bh_, s[nf]);
        s[nf] = mfma16(fqh[kk], bl_, s[nf]);
        s[nf] = mfma16(fql[kk], bh_, s[nf]);
      }
    }
    const float scale = 0.08838834764831845f;
    const bool need_mask = (k0 + 31 > q0);
    float p[2][4], alpha[4];
#pragma unroll
    for (int r = 0; r < 4; r++) {
      float s0 = s[0][r] * scale, s1 = s[1][r] * scale;
      if (need_mask) {
        int qi = q0 + w * 16 + ((l >> 4) << 2) + r;
        if (k0 + (l & 15) > qi) s0 = -1e30f;
        if (k0 + 16 + (l & 15) > qi) s1 = -1e30f;
      }
      float mt = fmaxf(s0, s1);
#pragma unroll
      for (int mk = 1; mk < 16; mk <<= 1) mt = fmaxf(mt, __shfl_xor(mt, mk));
      float mnew = fmaxf(m_run[r], mt);
      alpha[r] = expf(m_run[r] - mnew);
      float p0 = expf(s0 - mnew), p1 = expf(s1 - mnew);
      float rs = p0 + p1;
#pragma unroll
      for (int mk = 1; mk < 16; mk <<= 1) rs += __shfl_xor(rs, mk);
      l_run[r] = l_run[r] * alpha[r] + rs;
      m_run[r] = mnew;
      p[0][r] = p0; p[1][r] = p1;
    }
#pragma unroll
    for (int nf2 = 0; nf2 < 8; nf2++)
#pragma unroll
      for (int r = 0; r < 4; r++) acc[nf2][r] *= alpha[r];
    const int phb = PH + w * 640, plb = PL + w * 640;
#pragma unroll
    for (int nf = 0; nf < 2; nf++)
#pragma unroll
      for (int r = 0; r < 4; r++) {
        int row = ((l >> 4) << 2) + r, col = nf * 16 + (l & 15);
        __bf16 hi = (__bf16)p[nf][r];
        sm[phb + row * 40 + col] = hi;
        sm[plb + row * 40 + col] = (__bf16)(p[nf][r] - (float)hi);
      }
    bf16x8 aph = *(const bf16x8*)(sm + phb + (l & 15) * 40 + (l >> 4) * 8);
    bf16x8 apl = *(const bf16x8*)(sm + plb + (l & 15) * 40 + (l >> 4) * 8);
#pragma unroll
    for (int nf2 = 0; nf2 < 8; nf2++) {
      int drow = nf2 * 16 + (l & 15);
      bf16x8 bvh = *(const bf16x8*)(sm + VH + drow * 40 + (l >> 4) * 8);
      bf16x8 bvl = *(const bf16x8*)(sm + VL + drow * 40 + (l >> 4) * 8);
      acc[nf2] = mfma16(aph, bvh, acc[nf2]);
      acc[nf2] = mfma16(aph, bvl, acc[nf2]);
      acc[nf2] = mfma16(apl, bvh, acc[nf2]);
    }
  }
#pragma unroll
  for (int r = 0; r < 4; r++) {
    float inv = 1.0f / l_run[r];
    size_t t = q0 + w * 16 + ((l >> 4) << 2) + r;
#pragma unroll
    for (int nf2 = 0; nf2 < 8; nf2++)
      attn[t * 2048 + h * 128 + nf2 * 16 + (l & 15)] = acc[nf2][r] * inv;
  }
}

// ------------- router: fp32 logits, softmax, top-4 -------------
__global__ __launch_bounds__(256) void router_k(const float* __restrict__ h2,
                                                const float* __restrict__ rw,
                                                int* __restrict__ tidx, float* __restrict__ tw,
                                                int* __restrict__ counts) {
  int t = blockIdx.x;
  int e = threadIdx.x >> 3, sub = threadIdx.x & 7;
  const float* hrow = h2 + (size_t)t * 2048;
  const float* wrow = rw + (size_t)e * 2048;
  float acc = 0.0f;
  for (int d = sub * 4; d < 2048; d += 32) {
    float4 a = *(const float4*)(hrow + d);
    float4 b = *(const float4*)(wrow + d);
    acc += a.x * b.x + a.y * b.y + a.z * b.z + a.w * b.w;
  }
  acc += __shfl_xor(acc, 1); acc += __shfl_xor(acc, 2); acc += __shfl_xor(acc, 4);
  __shared__ float lg[32];
  if (sub == 0) lg[e] = acc;
  __syncthreads();
  if (threadIdx.x < 64) {
    int l = threadIdx.x;
    float v = (l < 32) ? lg[l] : -3e38f;
    float mx = v;
#pragma unroll
    for (int mk = 1; mk < 32; mk <<= 1) mx = fmaxf(mx, __shfl_xor(mx, mk));
    float ex = (l < 32) ? expf(v - mx) : 0.0f;
    float den = ex;
#pragma unroll
    for (int mk = 1; mk < 32; mk <<= 1) den += __shfl_xor(den, mk);
    float prob = ex / den;
    float pv = v;
    int sel_i[4]; float sel_w[4]; float wsum = 0.0f;
#pragma unroll
    for (int j = 0; j < 4; j++) {
      float m2 = pv;
#pragma unroll
      for (int mk = 1; mk < 32; mk <<= 1) m2 = fmaxf(m2, __shfl_xor(m2, mk));
      unsigned long long ball = __ballot((pv == m2) && (l < 32));
      int sel = __ffsll(ball) - 1;
      float ps = __shfl(prob, sel);
      sel_i[j] = sel; sel_w[j] = ps; wsum += ps;
      if (l == sel) pv = -3e38f;
    }
    if (l < 4) {
      tidx[t * 4 + l] = sel_i[l];
      tw[t * 4 + l] = sel_w[l] / (wsum + 1e-20f);
      atomicAdd(&counts[sel_i[l]], 1);
    }
  }
}

__global__ void zero_k(int* counts) { if (threadIdx.x < 32) counts[threadIdx.x] = 0; }

// scan + compact (expert, m-tile) schedule for BM=64 grouped GEMMs (<=96 pairs)
__global__ void scan_k(const int* __restrict__ counts, int* __restrict__ offs,
                       int* __restrict__ cursor, int* __restrict__ pair_e,
                       int* __restrict__ pair_mt) {
  int l = threadIdx.x;
  int c = (l < 32) ? counts[l] : 0;
  int x = c;
#pragma unroll
  for (int d = 1; d < 32; d <<= 1) {
    int y = __shfl_up(x, d);
    if (l >= d) x += y;
  }
  if (l < 32) { offs[l] = x - c; cursor[l] = 0; }
  if (l == 31) offs[32] = x;
  if (l == 0) {
    int n = 0;
    for (int e = 0; e < 32; e++) {
      int ce = counts[e];
      for (int m = 0; m * 64 < ce && n < 96; m++) { pair_e[n] = e; pair_mt[n] = m; n++; }
    }
    for (; n < 96; n++) { pair_e[n] = -1; pair_mt[n] = 0; }
  }
}

__global__ __launch_bounds__(256) void scatter_k(const int* __restrict__ tidx,
                                                 const int* __restrict__ offs,
                                                 int* __restrict__ cursor,
                                                 int* __restrict__ row_of_slot,
                                                 int* __restrict__ tok_of_row) {
  int p = blockIdx.x * 256 + threadIdx.x;
  if (p >= 4096) return;
  int e = tidx[p];
  int pos = atomicAdd(&cursor[e], 1);
  int row = offs[e] + pos;
  row_of_slot[p] = row;
  tok_of_row[row] = p >> 2;
}

// ------------- grouped gate/up GEMM: dbuf LDS, issue-early, BM=64 BN=128 BK=64 -------------
// 256 thr (4 waves 1x4, per-wave 64x32), grid (12 j, 96 pairs), 32 K-tiles
__global__ __launch_bounds__(256) void gateup_k(const __bf16* __restrict__ h2b,
                                                const float* __restrict__ wg,
                                                const float* __restrict__ wu,
                                                const int* __restrict__ counts,
                                                const int* __restrict__ offs,
                                                const int* __restrict__ tok_of_row,
                                                const int* __restrict__ pair_e,
                                                const int* __restrict__ pair_mt,
                                                float* __restrict__ gu) {
  const int p = blockIdx.y;
  const int e = pair_e[p];
  if (e < 0) return;
  const int mt = pair_mt[p];
  const int cnt = counts[e];
  const int j = blockIdx.x;
  const float* wsel = (j < 6) ? wg : wu;
  const int n0 = (j < 6 ? j : j - 6) * 128;
  const int gout = (j < 6) ? 0 : 768;
  __shared__ __align__(16) __bf16 smA0[64 * 72];
  __shared__ __align__(16) __bf16 smA1[64 * 72];
  __shared__ __align__(16) __bf16 smB0[128 * 72];
  __shared__ __align__(16) __bf16 smB1[128 * 72];
  __shared__ int toks[64];
  const int tid = threadIdx.x, l = tid & 63, w = tid >> 6;
  if (tid < 64) {
    int r = mt * 64 + tid;
    toks[tid] = (r < cnt) ? tok_of_row[offs[e] + r] : tok_of_row[offs[e]];
  }
  __syncthreads();
  const float* we = wsel + (size_t)e * 768 * 2048;
  const __bf16* aS[2];
  int aD[2];
#pragma unroll
  for (int i = 0; i < 2; i++) {
    aS[i] = h2b + (size_t)toks[(tid >> 3) + 32 * i] * 2048 + (tid & 7) * 8;
    aD[i] = ((tid >> 3) + 32 * i) * 72 + (tid & 7) * 8;
  }
  const float* bS[8];
  int bD[8];
#pragma unroll
  for (int i = 0; i < 8; i++) {
    bS[i] = we + (size_t)(n0 + (tid >> 4) + 16 * i) * 2048 + (tid & 15) * 4;
    bD[i] = ((tid >> 4) + 16 * i) * 72 + (tid & 15) * 4;
  }

  bf16x8 raE[2], raO[2];
  float4 rbE[8], rbO[8];

#define GU_ISSUE_E(kt) do { _Pragma("unroll") \
  for (int i = 0; i < 2; i++) raE[i] = *(const bf16x8*)(aS[i] + (kt)); \
  _Pragma("unroll") \
  for (int i = 0; i < 8; i++) rbE[i] = *(const float4*)(bS[i] + (kt)); } while (0)
#define GU_ISSUE_O(kt) do { _Pragma("unroll") \
  for (int i = 0; i < 2; i++) raO[i] = *(const bf16x8*)(aS[i] + (kt)); \
  _Pragma("unroll") \
  for (int i = 0; i < 8; i++) rbO[i] = *(const float4*)(bS[i] + (kt)); } while (0)
#define CVT4(dst, src) do { bf16x4 hv_; _Pragma("unroll") \
  for (int q_ = 0; q_ < 4; q_++) hv_[q_] = (__bf16)((const float*)&(src))[q_]; \
  *(bf16x4*)(dst) = hv_; } while (0)
#define GU_WRITE_E(smA, smB) do { _Pragma("unroll") \
  for (int i = 0; i < 2; i++) *(bf16x8*)(smA + aD[i]) = raE[i]; \
  _Pragma("unroll") \
  for (int i = 0; i < 8; i++) CVT4(smB + bD[i], rbE[i]); } while (0)
#define GU_WRITE_O(smA, smB) do { _Pragma("unroll") \
  for (int i = 0; i < 2; i++) *(bf16x8*)(smA + aD[i]) = raO[i]; \
  _Pragma("unroll") \
  for (int i = 0; i < 8; i++) CVT4(smB + bD[i], rbO[i]); } while (0)

  GU_ISSUE_E(0);
  GU_ISSUE_O(64);
  GU_WRITE_E(smA0, smB0);
  __syncthreads();

  f32x4 acc[4][2] = {};
  const int afo = ((l & 15)) * 72 + (l >> 4) * 8;
  const int bfo = (w * 32 + (l & 15)) * 72 + (l >> 4) * 8;
#define GU_COMPUTE(smA, smB) do { _Pragma("unroll") \
  for (int kk = 0; kk < 2; kk++) { \
    bf16x8 af_[4], bf_[2]; \
    _Pragma("unroll") \
    for (int f = 0; f < 4; f++) af_[f] = *(const bf16x8*)(smA + afo + kk * 32 + f * 1152); \
    _Pragma("unroll") \
    for (int f = 0; f < 2; f++) bf_[f] = *(const bf16x8*)(smB + bfo + kk * 32 + f * 1152); \
    _Pragma("unroll") \
    for (int mf = 0; mf < 4; mf++) \
      _Pragma("unroll") \
      for (int nf = 0; nf < 2; nf++) acc[mf][nf] = mfma16(af_[mf], bf_[nf], acc[mf][nf]); } \
} while (0)

  for (int it = 0; it < 32; it += 2) {
    GU_WRITE_O(smA1, smB1);
    if (it + 2 < 32) GU_ISSUE_E((it + 2) * 64);
    GU_COMPUTE(smA0, smB0);
    __syncthreads();
    if (it + 2 < 32) GU_WRITE_E(smA0, smB0);
    if (it + 3 < 32) GU_ISSUE_O((it + 3) * 64);
    GU_COMPUTE(smA1, smB1);
    __syncthreads();
  }
#undef GU_ISSUE_E
#undef GU_ISSUE_O
#undef GU_WRITE_E
#undef GU_WRITE_O
#undef GU_COMPUTE
#undef CVT4
#pragma unroll
  for (int mf = 0; mf < 4; mf++) {
    int rr = mt * 64 + mf * 16 + ((l >> 4) << 2);
#pragma unroll
    for (int nf = 0; nf < 2; nf++) {
      int col = gout + n0 + w * 32 + nf * 16 + (l & 15);
#pragma unroll
      for (int r = 0; r < 4; r++)
        if (rr + r < cnt)
          gu[(size_t)(offs[e] + rr + r) * 1536 + col] = acc[mf][nf][r];
    }
  }
}

// ------------- silu-mul: act[r][c] = silu(gu[r][c]) * gu[r][768+c] -------------
__global__ __launch_bounds__(192) void silu_k(const float* __restrict__ gu,
                                              __bf16* __restrict__ act) {
  int r = blockIdx.x, c = threadIdx.x * 4;
  float4 g = *(const float4*)(gu + (size_t)r * 1536 + c);
  float4 u = *(const float4*)(gu + (size_t)r * 1536 + 768 + c);
  bf16x4 o;
  o[0] = (__bf16)(g.x / (1.0f + expf(-g.x)) * u.x);
  o[1] = (__bf16)(g.y / (1.0f + expf(-g.y)) * u.y);
  o[2] = (__bf16)(g.z / (1.0f + expf(-g.z)) * u.z);
  o[3] = (__bf16)(g.w / (1.0f + expf(-g.w)) * u.w);
  *(bf16x4*)(act + (size_t)r * 768 + c) = o;
}

// ------------- grouped down GEMM: dbuf LDS, issue-early, BM=64 BN=128 BK=64 -------------
// 256 thr (4 waves 1x4), grid (16 nt, 96 pairs), 12 K-tiles
__global__ __launch_bounds__(256) void down_k(const __bf16* __restrict__ act,
                                              const float* __restrict__ wd,
                                              const int* __restrict__ counts,
                                              const int* __restrict__ offs,
                                              const int* __restrict__ pair_e,
                                              const int* __restrict__ pair_mt,
                                              float* __restrict__ dout) {
  const int p = blockIdx.y;
  const int e = pair_e[p];
  if (e < 0) return;
  const int mt = pair_mt[p];
  const int cnt = counts[e];
  const int n0 = blockIdx.x * 128;
  __shared__ __align__(16) __bf16 smA0[64 * 72];
  __shared__ __align__(16) __bf16 smA1[64 * 72];
  __shared__ __align__(16) __bf16 smB0[128 * 72];
  __shared__ __align__(16) __bf16 smB1[128 * 72];
  const int tid = threadIdx.x, l = tid & 63, w = tid >> 6;
  const float* wde = wd + (size_t)e * 2048 * 768;
  const int base = offs[e] + mt * 64;
  const __bf16* aS[2];
  int aD[2];
#pragma unroll
  for (int i = 0; i < 2; i++) {
    int rg = base + (tid >> 3) + 32 * i; if (rg > 4095) rg = 4095;
    aS[i] = act + (size_t)rg * 768 + (tid & 7) * 8;
    aD[i] = ((tid >> 3) + 32 * i) * 72 + (tid & 7) * 8;
  }
  const float* bS[8];
  int bD[8];
#pragma unroll
  for (int i = 0; i < 8; i++) {
    bS[i] = wde + (size_t)(n0 + (tid >> 4) + 16 * i) * 768 + (tid & 15) * 4;
    bD[i] = ((tid >> 4) + 16 * i) * 72 + (tid & 15) * 4;
  }

  bf16x8 raE[2], raO[2];
  float4 rbE[8], rbO[8];

#define DN_ISSUE_E(kt) do { _Pragma("unroll") \
  for (int i = 0; i < 2; i++) raE[i] = *(const bf16x8*)(aS[i] + (kt)); \
  _Pragma("unroll") \
  for (int i = 0; i < 8; i++) rbE[i] = *(const float4*)(bS[i] + (kt)); } while (0)
#define DN_ISSUE_O(kt) do { _Pragma("unroll") \
  for (int i = 0; i < 2; i++) raO[i] = *(const bf16x8*)(aS[i] + (kt)); \
  _Pragma("unroll") \
  for (int i = 0; i < 8; i++) rbO[i] = *(const float4*)(bS[i] + (kt)); } while (0)
#define CVT4(dst, src) do { bf16x4 hv_; _Pragma("unroll") \
  for (int q_ = 0; q_ < 4; q_++) hv_[q_] = (__bf16)((const float*)&(src))[q_]; \
  *(bf16x4*)(dst) = hv_; } while (0)
#define DN_WRITE_E(smA, smB) do { _Pragma("unroll") \
  for (int i = 0; i < 2; i++) *(bf16x8*)(smA + aD[i]) = raE[i]; \
  _Pragma("unroll") \
  for (int i = 0; i < 8; i++) CVT4(smB + bD[i], rbE[i]); } while (0)
#define DN_WRITE_O(smA, smB) do { _Pragma("unroll") \
  for (int i = 0; i < 2; i++) *(bf16x8*)(smA + aD[i]) = raO[i]; \
  _Pragma("unroll") \
  for (int i = 0; i < 8; i++) CVT4(smB + bD[i], rbO[i]); } while (0)

  DN_ISSUE_E(0);
  DN_ISSUE_O(64);
  DN_WRITE_E(smA0, smB0);
  __syncthreads();

  f32x4 acc[4][2] = {};
  const int afo = ((l & 15)) * 72 + (l >> 4) * 8;
  const int bfo = (w * 32 + (l & 15)) * 72 + (l >> 4) * 8;
#define DN_COMPUTE(smA, smB) do { _Pragma("unroll") \
  for (int kk = 0; kk < 2; kk++) { \
    bf16x8 af_[4], bf_[2]; \
    _Pragma("unroll") \
    for (int f = 0; f < 4; f++) af_[f] = *(const bf16x8*)(smA + afo + kk * 32 + f * 1152); \
    _Pragma("unroll") \
    for (int f = 0; f < 2; f++) bf_[f] = *(const bf16x8*)(smB + bfo + kk * 32 + f * 1152); \
    _Pragma("unroll") \
    for (int mf = 0; mf < 4; mf++) \
      _Pragma("unroll") \
      for (int nf = 0; nf < 2; nf++) acc[mf][nf] = mfma16(af_[mf], bf_[nf], acc[mf][nf]); } \
} while (0)

  for (int it = 0; it < 12; it += 2) {
    DN_WRITE_O(smA1, smB1);
    if (it + 2 < 12) DN_ISSUE_E((it + 2) * 64);
    DN_COMPUTE(smA0, smB0);
    __syncthreads();
    if (it + 2 < 12) DN_WRITE_E(smA0, smB0);
    if (it + 3 < 12) DN_ISSUE_O((it + 3) * 64);
    DN_COMPUTE(smA1, smB1);
    __syncthreads();
  }
#undef DN_ISSUE_E
#undef DN_ISSUE_O
#undef DN_WRITE_E
#undef DN_WRITE_O
#undef DN_COMPUTE
#undef CVT4
#pragma unroll
  for (int mf = 0; mf < 4; mf++) {
    int rr = mt * 64 + mf * 16 + ((l >> 4) << 2);
#pragma unroll
    for (int nf = 0; nf < 2; nf++) {
      int col = n0 + w * 32 + nf * 16 + (l & 15);
#pragma unroll
      for (int r = 0; r < 4; r++)
        if (rr + r < cnt)
          dout[(size_t)(offs[e] + rr + r) * 2048 + col] = acc[mf][nf][r];
    }
  }
}

// ------------- combine: out = hidden + sum_k w_k * dout[row_of_slot[t*4+k]] -------------
__global__ __launch_bounds__(256) void combine_k(const float* __restrict__ hidden,
                                                 const float* __restrict__ dout,
                                                 const int* __restrict__ row_of_slot,
                                                 const float* __restrict__ tw,
                                                 float* __restrict__ out) {
  int t = blockIdx.x;
  int r0 = row_of_slot[t * 4 + 0], r1 = row_of_slot[t * 4 + 1];
  int r2 = row_of_slot[t * 4 + 2], r3 = row_of_slot[t * 4 + 3];
  float w0 = tw[t * 4 + 0], w1 = tw[t * 4 + 1], w2 = tw[t * 4 + 2], w3 = tw[t * 4 + 3];
  const float* h = hidden + (size_t)t * 2048;
  float* o = out + (size_t)t * 2048;
  for (int d = threadIdx.x * 4; d < 2048; d += 1024) {
    float4 hv = *(const float4*)(h + d);
    float4 a0 = *(const float4*)(dout + (size_t)r0 * 2048 + d);
    float4 a1 = *(const float4*)(dout + (size_t)r1 * 2048 + d);
    float4 a2 = *(const float4*)(dout + (size_t)r2 * 2048 + d);
    float4 a3 = *(const float4*)(dout + (size_t)r3 * 2048 + d);
    float4 ov;
    ov.x = hv.x + w0 * a0.x + w1 * a1.x + w2 * a2.x + w3 * a3.x;
    ov.y = hv.y + w0 * a0.y + w1 * a1.y + w2 * a2.y + w3 * a3.y;
    ov.z = hv.z + w0 * a0.z + w1 * a1.z + w2 * a2.z + w3 * a3.z;
    ov.w = hv.w + w0 * a0.w + w1 * a1.w + w2 * a2.w + w3 * a3.w;
    *(float4*)(o + d) = ov;
  }
}

// ---------------- launcher ----------------
extern "C" void kernel_launch(void* const* d_in, const int* in_sizes, int n_in,
                              void* d_out, int out_size, void* d_ws, size_t ws_size,
                              hipStream_t stream) {
  (void)in_sizes; (void)n_in; (void)out_size; (void)ws_size;
  const float* hs   = (const float*)d_in[0];
  const int*   pos  = (const int*)d_in[1];
  const float* ln1w = (const float*)d_in[2];
  const float* wqkv = (const float*)d_in[3];
  const float* qnw  = (const float*)d_in[4];
  const float* knw  = (const float*)d_in[5];
  const float* wo   = (const float*)d_in[6];
  const float* ln2w = (const float*)d_in[7];
  const float* rw   = (const float*)d_in[8];
  const float* wg   = (const float*)d_in[9];
  const float* wu   = (const float*)d_in[10];
  const float* wd   = (const float*)d_in[11];
  float* out = (float*)d_out;
  char* ws = (char*)d_ws;

  float*  h1     = (float*)(ws + 0);
  float*  gu     = (float*)(ws + 0);           // [4096][1536] f32
  float*  dout   = (float*)(ws + 0);           // [4096][2048] f32 (after gu dead)
  float*  qkv    = (float*)(ws + 8388608);     // [1024][3072] f32 (dead after qkr_k)
  __bf16* qh     = (__bf16*)(ws + 20971520);
  __bf16* ql     = (__bf16*)(ws + 25165824);
  __bf16* kh     = (__bf16*)(ws + 29360128);
  __bf16* kl     = (__bf16*)(ws + 30408704);
  __bf16* vh     = (__bf16*)(ws + 31457280);
  __bf16* vl     = (__bf16*)(ws + 32505856);
  __bf16* vhT    = (__bf16*)(ws + 33554432);   // dead after flash_k
  __bf16* vlT    = (__bf16*)(ws + 34603008);
  int*    pair_e = (int*)(ws + 33554432);      // [96] (after vhT dead)
  int*    pair_mt= (int*)(ws + 33554944);      // [96]
  float*  attn   = (float*)(ws + 35651584);    // dead after O-proj
  __bf16* h2b    = (__bf16*)(ws + 35651584);   // [1024][2048] bf16 (rmsnorm2..gateup)
  __bf16* act    = (__bf16*)(ws + 35651584);   // [4096][768] bf16 (silu..down)
  float*  hidden = (float*)(ws + 44040192);
  float*  h2     = (float*)(ws + 52428800);
  int*    tidx   = (int*)(ws + 60817408);
  float*  tw     = (float*)(ws + 60833792);
  int*    counts = (int*)(ws + 60850176);
  int*    offs   = (int*)(ws + 60850432);
  int*    cursor = (int*)(ws + 60850688);
  int*    row_of_slot = (int*)(ws + 60850944);
  int*    tok_of_row  = (int*)(ws + 60867328);

  // attention block
  rmsnorm_k<<<1024, 256, 0, stream>>>(hs, ln1w, h1, nullptr);
  gemm3_k<<<dim3(8, 48), 256, 0, stream>>>(h1, wqkv, nullptr, qkv, 3072, 2048);
  qkr_k<<<dim3(24, 1024), 128, 0, stream>>>(qkv, pos, qnw, knw, qh, ql, kh, kl, vh, vl);
  vtrans_k<<<dim3(32, 4, 4), dim3(32, 32), 0, stream>>>(vh, vl, vhT, vlT);
  flash_k<<<dim3(16, 16), 256, 0, stream>>>(qh, ql, kh, kl, vhT, vlT, attn);
  gemm3_k<<<dim3(8, 32), 256, 0, stream>>>(attn, wo, hs, hidden, 2048, 2048);

  // MoE block
  rmsnorm_k<<<1024, 256, 0, stream>>>(hidden, ln2w, h2, h2b);
  zero_k<<<1, 64, 0, stream>>>(counts);
  router_k<<<1024, 256, 0, stream>>>(h2, rw, tidx, tw, counts);
  scan_k<<<1, 64, 0, stream>>>(counts, offs, cursor, pair_e, pair_mt);
  scatter_k<<<16, 256, 0, stream>>>(tidx, offs, cursor, row_of_slot, tok_of_row);
  gateup_k<<<dim3(12, 96), 256, 0, stream>>>(h2b, wg, wu, counts, offs, tok_of_row, pair_e, pair_mt, gu);
  silu_k<<<4096, 192, 0, stream>>>(gu, act);
  down_k<<<dim3(16, 96), 256, 0, stream>>>(act, wd, counts, offs, pair_e, pair_mt, dout);
  combine_k<<<1024, 256, 0, stream>>>(hidden, dout, row_of_slot, tw, out);
}